// Round 3
// baseline (7606.361 us; speedup 1.0000x reference)
//
#include <hip/hip_runtime.h>
#include <math.h>

typedef unsigned short u16;
typedef __attribute__((ext_vector_type(8))) short short8;
typedef __attribute__((ext_vector_type(4))) float f32x4;

#define D_    1024
#define H_    16
#define KH_   4
#define HD_   64
#define FF_   3072
#define L_    8
#define B_    2
#define S_    2048
#define W_    128
#define NTOK  4096

__device__ __forceinline__ float bf2f(u16 u) {
    union { unsigned int i; float f; } c; c.i = ((unsigned int)u) << 16; return c.f;
}
__device__ __forceinline__ u16 f2bf(float f) {
    unsigned int x = __float_as_uint(f);
    unsigned int r = x + 0x7fffu + ((x >> 16) & 1u);   // RNE
    return (u16)(r >> 16);
}

// ---------------------------------------------------------------------------
// dtype detection: stem_norm_w is all-ones.
// fp32 ones -> first dword 0x3F800000 ; bf16 ones -> 0x3F803F80
// ---------------------------------------------------------------------------
__global__ void detect_kernel(const unsigned int* __restrict__ w, int* __restrict__ flag)
{
    if (threadIdx.x == 0 && blockIdx.x == 0)
        flag[0] = (w[0] == 0x3F800000u) ? 1 : 0;   // 1 = inputs are fp32
}

// fp32 -> bf16 (active when flag==1)
__global__ __launch_bounds__(256)
void cvt_f32_kernel(const float* __restrict__ in, u16* __restrict__ out, int n,
                    const int* __restrict__ flag)
{
    if (flag[0] != 1) return;
    const int base = (blockIdx.x * 256 + threadIdx.x) * 8;
    if (base + 8 <= n) {
        const float4 a = ((const float4*)(in + base))[0];
        const float4 b = ((const float4*)(in + base))[1];
        ushort4 lo, hi;
        lo.x = f2bf(a.x); lo.y = f2bf(a.y); lo.z = f2bf(a.z); lo.w = f2bf(a.w);
        hi.x = f2bf(b.x); hi.y = f2bf(b.y); hi.z = f2bf(b.z); hi.w = f2bf(b.w);
        ((ushort4*)(out + base))[0] = lo;
        ((ushort4*)(out + base))[1] = hi;
    } else {
        for (int j = 0; j < 8 && base + j < n; ++j) out[base + j] = f2bf(in[base + j]);
    }
}

// bf16 -> bf16 copy (active when flag==0)
__global__ __launch_bounds__(256)
void copy_bf16_kernel(const u16* __restrict__ in, u16* __restrict__ out, int n,
                      const int* __restrict__ flag)
{
    if (flag[0] != 0) return;
    const int base = (blockIdx.x * 256 + threadIdx.x) * 8;
    if (base + 8 <= n) {
        ((int4*)(out + base))[0] = ((const int4*)(in + base))[0];
    } else {
        for (int j = 0; j < 8 && base + j < n; ++j) out[base + j] = in[base + j];
    }
}

// ---------------------------------------------------------------------------
// GEMM: C[M,N] = A[M,Kd] (bf16, row-major) @ B[Kd,N] (bf16, row-major)
// MODE 0: Cf = acc        MODE 1: Cb = bf16(acc)
// MODE 2: Cf = resf + acc MODE 3: Cf = bf2f(resb) + scale*acc
// ---------------------------------------------------------------------------
#define BM 128
#define BN 128
#define BK 32
#define LDK 40   // padded LDS stride (elements)

template<int MODE>
__global__ __launch_bounds__(256, 2)
void gemm_kernel(const u16* __restrict__ A, const u16* __restrict__ B,
                 int M, int N, int Kd,
                 float* Cf, u16* __restrict__ Cb,
                 const float* resf, const u16* __restrict__ resb,
                 const u16* __restrict__ scale_ptr)
{
    __shared__ __align__(16) u16 As[BM][LDK];
    __shared__ __align__(16) u16 Bs[BN][LDK];

    const int tid  = threadIdx.x;
    const int bn   = blockIdx.x * BN;
    const int bm   = blockIdx.y * BM;
    const int lane = tid & 63;
    const int wave = tid >> 6;
    const int wm   = (wave & 1) * 64;
    const int wn   = (wave >> 1) * 64;
    const int lm   = lane & 15;
    const int q8   = lane >> 4;

    const f32x4 zero = {0.f, 0.f, 0.f, 0.f};
    f32x4 acc[4][4];
#pragma unroll
    for (int i = 0; i < 4; ++i)
#pragma unroll
        for (int j = 0; j < 4; ++j) acc[i][j] = zero;

    // staging assignments
    const int am  = tid >> 1;          // 0..127 (A row in tile)
    const int ak  = (tid & 1) * 16;    // 0 / 16 (A col chunk)
    const int bnl = tid & 127;         // 0..127 (B col in tile)
    const int bh  = tid >> 7;          // 0 / 1  (B k half)

    for (int k0 = 0; k0 < Kd; k0 += BK) {
        // global loads to regs
        const u16* asrc = A + (size_t)(bm + am) * Kd + k0 + ak;
        int4 av0 = ((const int4*)asrc)[0];
        int4 av1 = ((const int4*)asrc)[1];

        const u16* bsrc = B + (size_t)(k0 + bh * 16) * N + bn + bnl;
        unsigned int pk[8];
#pragma unroll
        for (int kk = 0; kk < 8; ++kk) {
            u16 lo_ = bsrc[(size_t)(2 * kk) * N];
            u16 hi_ = bsrc[(size_t)(2 * kk + 1) * N];
            pk[kk] = (unsigned int)lo_ | ((unsigned int)hi_ << 16);
        }
        int4 bv0; bv0.x = (int)pk[0]; bv0.y = (int)pk[1]; bv0.z = (int)pk[2]; bv0.w = (int)pk[3];
        int4 bv1; bv1.x = (int)pk[4]; bv1.y = (int)pk[5]; bv1.z = (int)pk[6]; bv1.w = (int)pk[7];

        __syncthreads();
        ((int4*)&As[am][ak])[0]       = av0;
        ((int4*)&As[am][ak])[1]       = av1;
        ((int4*)&Bs[bnl][bh * 16])[0] = bv0;
        ((int4*)&Bs[bnl][bh * 16])[1] = bv1;
        __syncthreads();

        short8 af[4], bf_[4];
#pragma unroll
        for (int i = 0; i < 4; ++i)
            af[i] = *(const short8*)&As[wm + i * 16 + lm][q8 * 8];
#pragma unroll
        for (int j = 0; j < 4; ++j)
            bf_[j] = *(const short8*)&Bs[wn + j * 16 + lm][q8 * 8];
#pragma unroll
        for (int i = 0; i < 4; ++i)
#pragma unroll
            for (int j = 0; j < 4; ++j)
                acc[i][j] = __builtin_amdgcn_mfma_f32_16x16x32_bf16(af[i], bf_[j], acc[i][j], 0, 0, 0);
    }

    float scale = 1.f;
    if (MODE == 3) scale = bf2f(scale_ptr[0]);

#pragma unroll
    for (int i = 0; i < 4; ++i) {
        const int grow0 = bm + wm + i * 16 + q8 * 4;
#pragma unroll
        for (int j = 0; j < 4; ++j) {
            const int gcol = bn + wn + j * 16 + lm;
#pragma unroll
            for (int r = 0; r < 4; ++r) {
                const size_t idx = (size_t)(grow0 + r) * N + gcol;
                const float v = acc[i][j][r];
                if (MODE == 0) Cf[idx] = v;
                if (MODE == 1) Cb[idx] = f2bf(v);
                if (MODE == 2) Cf[idx] = resf[idx] + v;
                if (MODE == 3) Cf[idx] = bf2f(resb[idx]) + scale * v;
            }
        }
    }
}

// ---------------------------------------------------------------------------
// RMSNorm: one block per row of 1024
// ---------------------------------------------------------------------------
template<int INBF, int OUTBF>
__global__ __launch_bounds__(256)
void rmsnorm_kernel(const void* __restrict__ xin, const u16* __restrict__ w,
                    void* __restrict__ out)
{
    const int row = blockIdx.x;
    const int tid = threadIdx.x;
    float v0, v1, v2, v3;
    if (INBF) {
        const ushort4 u = ((const ushort4*)((const u16*)xin + (size_t)row * D_))[tid];
        v0 = bf2f(u.x); v1 = bf2f(u.y); v2 = bf2f(u.z); v3 = bf2f(u.w);
    } else {
        const float4 f = ((const float4*)((const float*)xin + (size_t)row * D_))[tid];
        v0 = f.x; v1 = f.y; v2 = f.z; v3 = f.w;
    }
    float ss = v0 * v0 + v1 * v1 + v2 * v2 + v3 * v3;
#pragma unroll
    for (int off = 32; off > 0; off >>= 1) ss += __shfl_down(ss, off, 64);
    __shared__ float red[4];
    const int wv = tid >> 6, ln = tid & 63;
    if (ln == 0) red[wv] = ss;
    __syncthreads();
    const float tot = red[0] + red[1] + red[2] + red[3];
    const float inv = rsqrtf(tot * (1.f / 1024.f) + 1e-6f);
    const ushort4 wu = ((const ushort4*)w)[tid];
    const float o0 = v0 * inv * bf2f(wu.x);
    const float o1 = v1 * inv * bf2f(wu.y);
    const float o2 = v2 * inv * bf2f(wu.z);
    const float o3 = v3 * inv * bf2f(wu.w);
    if (OUTBF) {
        ushort4 ou; ou.x = f2bf(o0); ou.y = f2bf(o1); ou.z = f2bf(o2); ou.w = f2bf(o3);
        ((ushort4*)((u16*)out + (size_t)row * D_))[tid] = ou;
    } else {
        float4 of; of.x = o0; of.y = o1; of.z = o2; of.w = o3;
        ((float4*)((float*)out + (size_t)row * D_))[tid] = of;
    }
}

// ---------------------------------------------------------------------------
// depthwise causal conv K=5 over fp32 rms output -> bf16
// ---------------------------------------------------------------------------
__global__ __launch_bounds__(256)
void dwconv_kernel(const float* __restrict__ rms, const u16* __restrict__ dw,
                   u16* __restrict__ outb)
{
    const int idx = blockIdx.x * 256 + threadIdx.x;     // over NTOK*1024
    const int d = idx & 1023;
    const int t = idx >> 10;
    const int s = t & (S_ - 1);
    float acc = 0.f;
#pragma unroll
    for (int k = 0; k < 5; ++k) {
        const int sp = s - 4 + k;
        if (sp >= 0) acc += rms[(size_t)(t - 4 + k) * D_ + d] * bf2f(dw[d * 5 + k]);
    }
    outb[idx] = f2bf(acc);
}

// ---------------------------------------------------------------------------
// bf16 transpose: out[c][r] = in[r][c]
// ---------------------------------------------------------------------------
__global__ __launch_bounds__(256)
void transpose_bf16(const u16* __restrict__ in, u16* __restrict__ out, int R, int C)
{
    __shared__ u16 tile[32][33];
    const int x  = threadIdx.x & 31;
    const int y0 = (threadIdx.x >> 5) * 4;
    const int rb = blockIdx.y * 32, cb = blockIdx.x * 32;
#pragma unroll
    for (int j = 0; j < 4; ++j)
        tile[y0 + j][x] = in[(size_t)(rb + y0 + j) * C + cb + x];
    __syncthreads();
#pragma unroll
    for (int j = 0; j < 4; ++j)
        out[(size_t)(cb + y0 + j) * R + rb + x] = tile[x][y0 + j];
}

// ---------------------------------------------------------------------------
// RoPE in place on fp32 [tok][nh*64]
// ---------------------------------------------------------------------------
template<int NH>
__global__ __launch_bounds__(256)
void rope_kernel(float* __restrict__ buf)
{
    constexpr int SH = (NH == 16) ? 9 : 7;
    const int idx = blockIdx.x * 256 + threadIdx.x;     // over NTOK*NH*32
    const int j  = idx & 31;
    const int hh = (idx >> 5) & (NH - 1);
    const int t  = idx >> SH;
    const int pos = t & (S_ - 1);
    const float inv = powf(10000.f, -(float)j * (1.f / 32.f));
    const float fr = (float)pos * inv;
    float sn, cs;
    sincosf(fr, &sn, &cs);
    const size_t base = (size_t)t * (NH * 64) + hh * 64 + j;
    const float x1 = buf[base], x2 = buf[base + 32];
    buf[base]      = x1 * cs + x2 * sn;
    buf[base + 32] = x2 * cs - x1 * sn;
}

// ---------------------------------------------------------------------------
// sliding-window attention: keys j in [t-127, t], GQA 4:1
// one thread per query, one block per (window-block, head, batch)
// ---------------------------------------------------------------------------
__global__ __launch_bounds__(128, 2)
void attn_kernel(const float* __restrict__ q, const float* __restrict__ kk_,
                 const float* __restrict__ vv_, u16* __restrict__ outb)
{
    const int nblk = blockIdx.x, hh = blockIdx.y, b = blockIdx.z;
    const int p = threadIdx.x;
    const int t = nblk * W_ + p;
    const int kh = hh >> 2;
    const size_t tok = (size_t)b * S_ + t;
    const float* qp = q + tok * (H_ * HD_) + hh * HD_;
    float qr[64];
#pragma unroll
    for (int i = 0; i < 16; ++i) {
        const float4 f = ((const float4*)qp)[i];
        qr[4 * i] = f.x; qr[4 * i + 1] = f.y; qr[4 * i + 2] = f.z; qr[4 * i + 3] = f.w;
    }
    float o[64];
#pragma unroll
    for (int i = 0; i < 64; ++i) o[i] = 0.f;
    float mx = -1e30f, l = 0.f;
    int lo = t - (W_ - 1); if (lo < 0) lo = 0;
    for (int j = lo; j <= t; ++j) {
        const float* kp = kk_ + ((size_t)b * S_ + j) * (KH_ * HD_) + kh * HD_;
        float s = 0.f;
#pragma unroll
        for (int i = 0; i < 16; ++i) {
            const float4 f = ((const float4*)kp)[i];
            s += qr[4 * i] * f.x + qr[4 * i + 1] * f.y + qr[4 * i + 2] * f.z + qr[4 * i + 3] * f.w;
        }
        s *= 0.125f;
        const float mn = fmaxf(mx, s);
        const float corr = __expf(mx - mn);
        const float pr = __expf(s - mn);
        l = l * corr + pr;
        mx = mn;
        const float* vp = vv_ + ((size_t)b * S_ + j) * (KH_ * HD_) + kh * HD_;
#pragma unroll
        for (int i = 0; i < 16; ++i) {
            const float4 f = ((const float4*)vp)[i];
            o[4 * i]     = o[4 * i] * corr     + pr * f.x;
            o[4 * i + 1] = o[4 * i + 1] * corr + pr * f.y;
            o[4 * i + 2] = o[4 * i + 2] * corr + pr * f.z;
            o[4 * i + 3] = o[4 * i + 3] * corr + pr * f.w;
        }
    }
    const float invl = 1.f / l;
    u16* op = outb + tok * (H_ * HD_) + hh * HD_;
#pragma unroll
    for (int i = 0; i < 64; ++i) op[i] = f2bf(o[i] * invl);
}

// ---------------------------------------------------------------------------
// gg = silu(g1) * g3 (in place into g1)
// ---------------------------------------------------------------------------
__global__ __launch_bounds__(256)
void silu_mul_kernel(u16* __restrict__ g1, const u16* __restrict__ g3)
{
    const int idx = blockIdx.x * 256 + threadIdx.x;
    const float a = bf2f(g1[idx]);
    const float b = bf2f(g3[idx]);
    const float s = a / (1.f + __expf(-a));
    g1[idx] = f2bf(s * b);
}

// ---------------------------------------------------------------------------
extern "C" void kernel_launch(void* const* d_in, const int* in_sizes, int n_in,
                              void* d_out, int out_size, void* d_ws, size_t ws_size,
                              hipStream_t stream)
{
    char* ws = (char*)d_ws;
    size_t off = 0;
    auto alloc = [&](size_t bytes) -> void* {
        void* p = ws + off;
        off = (off + bytes + 255) & ~(size_t)255;
        return p;
    };

    int* flag = (int*)alloc(256);

    // canonical bf16 copies of all 15 inputs
    static const int N_IN = 15;
    u16* c[N_IN];
    int sizes[N_IN];
    for (int i = 0; i < N_IN; ++i) {
        sizes[i] = in_sizes[i];
        c[i] = (u16*)alloc((size_t)sizes[i] * 2);
    }

    float* h    = (float*)alloc((size_t)NTOK * D_ * 4);
    float* qb   = (float*)alloc((size_t)NTOK * (H_ * HD_) * 4);
    float* kb   = (float*)alloc((size_t)NTOK * (KH_ * HD_) * 4);
    float* vb   = (float*)alloc((size_t)NTOK * (KH_ * HD_) * 4);
    u16*   abuf = (u16*)alloc((size_t)NTOK * D_ * 2);
    u16*   aob  = (u16*)alloc((size_t)NTOK * (H_ * HD_) * 2);
    u16*   g1b  = (u16*)alloc((size_t)NTOK * FF_ * 2);
    u16*   g3b  = (u16*)alloc((size_t)NTOK * FF_ * 2);
    u16*   pwT  = (u16*)alloc((size_t)D_ * D_ * 2);
    (void)ws_size; (void)n_in; (void)out_size;

    // ---- dtype detect + normalize every input to bf16 ----
    detect_kernel<<<1, 64, 0, stream>>>((const unsigned int*)d_in[1], flag);
    for (int i = 0; i < N_IN; ++i) {
        const int blocks = (sizes[i] + 2047) / 2048;
        cvt_f32_kernel<<<blocks, 256, 0, stream>>>((const float*)d_in[i], c[i], sizes[i], flag);
        copy_bf16_kernel<<<blocks, 256, 0, stream>>>((const u16*)d_in[i], c[i], sizes[i], flag);
    }

    const u16* x      = c[0];
    const u16* snw    = c[1];
    const u16* sdw    = c[2];
    const u16* spw    = c[3];
    const u16* sscale = c[4];
    const u16* anw    = c[5];
    const u16* wq     = c[6];
    const u16* wk     = c[7];
    const u16* wv     = c[8];
    const u16* wo     = c[9];
    const u16* fnw    = c[10];
    const u16* w1     = c[11];
    const u16* w3     = c[12];
    const u16* w2     = c[13];
    const u16* finw   = c[14];

    // ---- conv stem ----
    transpose_bf16<<<dim3(32, 32), 256, 0, stream>>>(spw, pwT, D_, D_);
    rmsnorm_kernel<1, 0><<<NTOK, 256, 0, stream>>>((const void*)x, snw, (void*)qb);
    dwconv_kernel<<<(NTOK * D_) / 256, 256, 0, stream>>>(qb, sdw, abuf);
    gemm_kernel<3><<<dim3(D_ / BN, NTOK / BM), 256, 0, stream>>>(
        abuf, pwT, NTOK, D_, D_, h, nullptr, nullptr, x, sscale);

    // ---- layers ----
    for (int l = 0; l < L_; ++l) {
        rmsnorm_kernel<0, 1><<<NTOK, 256, 0, stream>>>((const void*)h, anw + (size_t)l * D_, (void*)abuf);
        gemm_kernel<0><<<dim3((H_ * HD_) / BN, NTOK / BM), 256, 0, stream>>>(
            abuf, wq + (size_t)l * D_ * (H_ * HD_), NTOK, H_ * HD_, D_, qb, nullptr, nullptr, nullptr, nullptr);
        gemm_kernel<0><<<dim3((KH_ * HD_) / BN, NTOK / BM), 256, 0, stream>>>(
            abuf, wk + (size_t)l * D_ * (KH_ * HD_), NTOK, KH_ * HD_, D_, kb, nullptr, nullptr, nullptr, nullptr);
        gemm_kernel<0><<<dim3((KH_ * HD_) / BN, NTOK / BM), 256, 0, stream>>>(
            abuf, wv + (size_t)l * D_ * (KH_ * HD_), NTOK, KH_ * HD_, D_, vb, nullptr, nullptr, nullptr, nullptr);
        rope_kernel<H_><<<(NTOK * H_ * 32) / 256, 256, 0, stream>>>(qb);
        rope_kernel<KH_><<<(NTOK * KH_ * 32) / 256, 256, 0, stream>>>(kb);
        attn_kernel<<<dim3(S_ / W_, H_, B_), 128, 0, stream>>>(qb, kb, vb, aob);
        gemm_kernel<2><<<dim3(D_ / BN, NTOK / BM), 256, 0, stream>>>(
            aob, wo + (size_t)l * (H_ * HD_) * D_, NTOK, D_, H_ * HD_, h, nullptr, h, nullptr, nullptr);
        rmsnorm_kernel<0, 1><<<NTOK, 256, 0, stream>>>((const void*)h, fnw + (size_t)l * D_, (void*)abuf);
        gemm_kernel<1><<<dim3(FF_ / BN, NTOK / BM), 256, 0, stream>>>(
            abuf, w1 + (size_t)l * D_ * FF_, NTOK, FF_, D_, nullptr, g1b, nullptr, nullptr, nullptr);
        gemm_kernel<1><<<dim3(FF_ / BN, NTOK / BM), 256, 0, stream>>>(
            abuf, w3 + (size_t)l * D_ * FF_, NTOK, FF_, D_, nullptr, g3b, nullptr, nullptr, nullptr);
        silu_mul_kernel<<<(NTOK * FF_) / 256, 256, 0, stream>>>(g1b, g3b);
        gemm_kernel<2><<<dim3(D_ / BN, NTOK / BM), 256, 0, stream>>>(
            g1b, w2 + (size_t)l * FF_ * D_, NTOK, D_, FF_, h, nullptr, h, nullptr, nullptr);
    }

    // ---- final norm: OUTPUT IS FP32 (reference output dtype) ----
    rmsnorm_kernel<0, 0><<<NTOK, 256, 0, stream>>>((const void*)h, finw, d_out);
}